// Round 3
// baseline (2999.223 us; speedup 1.0000x reference)
//
#include <hip/hip_runtime.h>
#include <math.h>

#define C 40

// ---------------- mask dtype detection ----------------
__global__ void k_detect(const unsigned int* __restrict__ w, int nwords,
                         unsigned int* __restrict__ flags) {
    int i = blockIdx.x * blockDim.x + threadIdx.x;
    unsigned int viol = 0;
    for (; i < nwords; i += gridDim.x * blockDim.x) {
        unsigned int v = w[i];
        if (!(v == 0u || v == 1u)) viol |= 1u;
        if (!(v == 0u || v == 0x3F800000u)) viol |= 2u;
    }
    if (viol) atomicOr(flags, viol);
}

__device__ __forceinline__ bool read_mask(const void* mp, unsigned int fl, int n) {
    if ((fl & 1u) == 0u) return ((const int*)mp)[n] != 0;        // int32 {0,1}
    if ((fl & 2u) == 0u) return ((const float*)mp)[n] != 0.0f;   // float {0,1}
    return ((const unsigned char*)mp)[n] != 0;                   // bool bytes
}

// ---------------- degree / norm ----------------
__global__ void k_deg(const int* __restrict__ dst, int* __restrict__ deg, int E) {
    int i = blockIdx.x * blockDim.x + threadIdx.x;
    if (i < E) atomicAdd(&deg[dst[i]], 1);
}

__global__ void k_dinv(const int* __restrict__ deg, float* __restrict__ dinv, int n) {
    int i = blockIdx.x * blockDim.x + threadIdx.x;
    if (i < n) {
        int d = deg[i];
        dinv[i] = (d > 0) ? rsqrtf((float)d) : 0.0f;
    }
}

// ---------------- exclusive scan (3-phase) over deg -> rowptr ----------------
__global__ void k_scan1(const int* __restrict__ deg, int* __restrict__ rowptr,
                        int* __restrict__ bsum, int n) {
    __shared__ int sm[256];
    int tid = threadIdx.x;
    int i = blockIdx.x * 256 + tid;
    int v = (i < n) ? deg[i] : 0;
    sm[tid] = v;
    __syncthreads();
#pragma unroll
    for (int o = 1; o < 256; o <<= 1) {
        int t = (tid >= o) ? sm[tid - o] : 0;
        __syncthreads();
        sm[tid] += t;
        __syncthreads();
    }
    if (i <= n) rowptr[i] = sm[tid] - v;  // exclusive
    if (tid == 255) bsum[blockIdx.x] = sm[255];
}

__global__ void k_scan2(int* __restrict__ bsum, int nb) {
    __shared__ int sm[512];
    int tid = threadIdx.x;
    int v = (tid < nb) ? bsum[tid] : 0;
    sm[tid] = v;
    __syncthreads();
    for (int o = 1; o < 512; o <<= 1) {
        int t = (tid >= o) ? sm[tid - o] : 0;
        __syncthreads();
        sm[tid] += t;
        __syncthreads();
    }
    if (tid < nb) bsum[tid] = sm[tid] - v;  // exclusive over block sums
}

__global__ void k_scan3(int* __restrict__ rowptr, const int* __restrict__ bsum, int n) {
    int i = blockIdx.x * 256 + threadIdx.x;
    if (i <= n) rowptr[i] += bsum[blockIdx.x];
}

// ---------------- CSR scatter: pk[pos] = {src, norm} ----------------
__global__ void k_csr(const int* __restrict__ src, const int* __restrict__ dst,
                      const float* __restrict__ dinv, const int* __restrict__ rowptr,
                      int* __restrict__ fill, int2* __restrict__ pk, int E) {
    int e = blockIdx.x * blockDim.x + threadIdx.x;
    if (e < E) {
        int s = src[e], d = dst[e];
        int pos = rowptr[d] + atomicAdd(&fill[d], 1);
        int2 v = make_int2(s, __float_as_int(dinv[s] * dinv[d]));
        __builtin_nontemporal_store(*(long long*)&v, (long long*)&pk[pos]);
    }
}

// ---------------- error + block partials (no global atomics) ----------------
__global__ __launch_bounds__(256) void k_error(
    const float4* __restrict__ ys4, const int* __restrict__ y_true,
    const void* __restrict__ maskp, const unsigned int* __restrict__ flags,
    float4* __restrict__ err4, float* __restrict__ psig, float* __restrict__ pcnt,
    int nquads) {
    unsigned int fl = *flags;
    float a = 0.f, cnt = 0.f;
    for (int i = blockIdx.x * blockDim.x + threadIdx.x; i < nquads;
         i += gridDim.x * blockDim.x) {
        int node = i / 10;
        int q = i - node * 10;
        float4 e = make_float4(0.f, 0.f, 0.f, 0.f);
        if (read_mask(maskp, fl, node)) {
            int yt = y_true[node];
            float4 ys = ys4[i];
            int c0 = q * 4;
            e.x = ((c0 + 0) == yt ? 1.f : 0.f) - ys.x;
            e.y = ((c0 + 1) == yt ? 1.f : 0.f) - ys.y;
            e.z = ((c0 + 2) == yt ? 1.f : 0.f) - ys.z;
            e.w = ((c0 + 3) == yt ? 1.f : 0.f) - ys.w;
            a += fabsf(e.x) + fabsf(e.y) + fabsf(e.z) + fabsf(e.w);
            if (q == 0) cnt += 1.f;
        }
        err4[i] = e;
    }
    __shared__ float sA[256];
    __shared__ float sC[256];
    int tid = threadIdx.x;
    sA[tid] = a; sC[tid] = cnt;
    __syncthreads();
    for (int o = 128; o; o >>= 1) {
        if (tid < o) { sA[tid] += sA[tid + o]; sC[tid] += sC[tid + o]; }
        __syncthreads();
    }
    if (tid == 0) { psig[blockIdx.x] = sA[0]; pcnt[blockIdx.x] = sC[0]; }
}

__global__ __launch_bounds__(256) void k_reduce(
    const float* __restrict__ psig, const float* __restrict__ pcnt,
    float* __restrict__ s_sig, float* __restrict__ s_cnt, int nb) {
    float a = 0.f, c = 0.f;
    for (int i = threadIdx.x; i < nb; i += 256) { a += psig[i]; c += pcnt[i]; }
    __shared__ float sA[256];
    __shared__ float sC[256];
    int tid = threadIdx.x;
    sA[tid] = a; sC[tid] = c;
    __syncthreads();
    for (int o = 128; o; o >>= 1) {
        if (tid < o) { sA[tid] += sA[tid + o]; sC[tid] += sC[tid + o]; }
        __syncthreads();
    }
    if (tid == 0) { *s_sig = sA[0]; *s_cnt = sC[0]; }
}

// ---------------- propagation layer: one wave per dst node ----------------
// 3-stage software pipeline over 8-edge groups:
//   issue pk[g+2] | gather x[g+1] | FMA g
// pk/y0/out use nontemporal hints so L2 keeps the x feature rows.
#define LOADPK(S, NRM, EE)                                                   \
    _Pragma("unroll") for (int j = 0; j < 8; ++j) {                          \
        unsigned long long u =                                               \
            __builtin_nontemporal_load(pk8 + (EE) + j);                      \
        S[j] = (int)(u & 0xffffffffu);                                       \
        NRM[j] = __int_as_float((int)(u >> 32));                             \
    }

#define GATHER(XV, S)                                                        \
    _Pragma("unroll") for (int j = 0; j < 8; ++j) {                          \
        XV[j] = x[S[j] * C + lane];                                          \
    }

#define FMA8(NRM, XV)                                                        \
    _Pragma("unroll") for (int j = 0; j < 8; ++j) {                          \
        acc[j & 3] = fmaf(NRM[j], XV[j], acc[j & 3]);                        \
    }

template <int POST>
__global__ __launch_bounds__(256, 4) void k_prop(
    const int* __restrict__ rowptr, const unsigned long long* __restrict__ pk8,
    const float* __restrict__ x, const float* __restrict__ y0,
    float* __restrict__ out, float alpha, float beta, int n) {
    int wid = (blockIdx.x * blockDim.x + threadIdx.x) >> 6;
    int lane = threadIdx.x & 63;
    if (wid >= n) return;
    int beg = rowptr[wid], end = rowptr[wid + 1];
    float v = 0.f;
    if (lane < C) {
        float y0v = __builtin_nontemporal_load(y0 + wid * C + lane);
        float acc[4] = {0.f, 0.f, 0.f, 0.f};
        int e = beg;
        int nf = (end - beg) >> 3;  // full groups of 8
        if (nf == 1) {
            int sA[8]; float nA[8], xA[8];
            LOADPK(sA, nA, e)
            GATHER(xA, sA)
            FMA8(nA, xA)
            e += 8;
        } else if (nf >= 2) {
            int sA[8], sB[8];
            float nA[8], nB[8], xA[8];
            LOADPK(sA, nA, e)
            LOADPK(sB, nB, e + 8)
            GATHER(xA, sA)
            int g = nf - 2;
            while (g-- > 0) {
                int sC_[8]; float nC_[8], xB[8];
                LOADPK(sC_, nC_, e + 16)
                GATHER(xB, sB)
                FMA8(nA, xA)
#pragma unroll
                for (int j = 0; j < 8; ++j) {
                    sA[j] = sB[j]; nA[j] = nB[j]; xA[j] = xB[j];
                    sB[j] = sC_[j]; nB[j] = nC_[j];
                }
                e += 8;
            }
            float xB[8];
            GATHER(xB, sB)
            FMA8(nA, xA)
            FMA8(nB, xB)
            e += 16;
        }
        for (; e < end; ++e) {
            unsigned long long u = __builtin_nontemporal_load(pk8 + e);
            int s = (int)(u & 0xffffffffu);
            float nrm = __int_as_float((int)(u >> 32));
            acc[0] = fmaf(nrm, x[s * C + lane], acc[0]);
        }
        float a = (acc[0] + acc[1]) + (acc[2] + acc[3]);
        v = fmaf(alpha, a, beta * y0v);
    }
    if (POST == 0) {
        if (lane < C)
            __builtin_nontemporal_store(fminf(1.0f, fmaxf(-1.0f, v)),
                                        out + wid * C + lane);
    } else {
        float mx = (lane < C) ? v : -3.0e38f;
#pragma unroll
        for (int o = 32; o; o >>= 1) mx = fmaxf(mx, __shfl_xor(mx, o));
        float ex = (lane < C) ? __expf(v - mx) : 0.0f;
        float s = ex;
#pragma unroll
        for (int o = 32; o; o >>= 1) s += __shfl_xor(s, o);
        if (lane < C)
            __builtin_nontemporal_store(ex / s, out + wid * C + lane);
    }
}

// ---------------- scale + y0 build: one wave per node ----------------
__global__ __launch_bounds__(256) void k_scale(
    const float* __restrict__ sm_err, const float* __restrict__ y_soft,
    const int* __restrict__ y_true, const void* __restrict__ maskp,
    const unsigned int* __restrict__ flags, const float* __restrict__ s_sig,
    const float* __restrict__ s_cnt, float* __restrict__ y0, int n) {
    int wid = (blockIdx.x * blockDim.x + threadIdx.x) >> 6;
    int lane = threadIdx.x & 63;
    if (wid >= n) return;
    float v = 0.f, a = 0.f;
    if (lane < C) {
        v = sm_err[wid * C + lane];
        a = fabsf(v);
    }
#pragma unroll
    for (int o = 32; o; o >>= 1) a += __shfl_xor(a, o);
    float sigma = (*s_sig) / (*s_cnt);
    float scale = sigma / a;
    if (isinf(scale) || scale > 1000.0f) scale = 1.0f;
    if (lane < C) {
        bool m = read_mask(maskp, *flags, wid);
        float yc = fmaf(scale, v, y_soft[wid * C + lane]);
        y0[wid * C + lane] = m ? ((lane == y_true[wid]) ? 1.0f : 0.0f) : yc;
    }
}

extern "C" void kernel_launch(void* const* d_in, const int* in_sizes, int n_in,
                              void* d_out, int out_size, void* d_ws, size_t ws_size,
                              hipStream_t stream) {
    const int* y_true = (const int*)d_in[0];
    const float* y_soft = (const float*)d_in[1];
    const void* maskp = d_in[2];
    const int* ei = (const int*)d_in[3];
    const int n = in_sizes[0];
    const int total = in_sizes[1];          // n * C
    const int E = in_sizes[3] / 2;
    const int* src = ei;
    const int* dst = ei + E;

    char* ws = (char*)d_ws;
    size_t off = 0;
    auto alloc = [&](size_t bytes) -> char* {
        char* p = ws + off;
        off += (bytes + 63) & ~(size_t)63;
        return p;
    };
    int* deg = (int*)alloc((size_t)n * 4);
    int* fill = (int*)alloc((size_t)n * 4);
    unsigned int* flags = (unsigned int*)alloc(4);
    size_t zero_bytes = off;                 // zero everything above each call
    float* s_sig = (float*)alloc(4);
    float* s_cnt = (float*)alloc(4);
    float* psig = (float*)alloc(2048 * 4);
    float* pcnt = (float*)alloc(2048 * 4);
    float* dinv = (float*)alloc((size_t)n * 4);
    int* rowptr = (int*)alloc((size_t)(n + 1) * 4);
    int* bsum = (int*)alloc(4096);
    int2* pk = (int2*)alloc((size_t)E * 8);
    float* bufA = (float*)alloc((size_t)total * 4);
    float* bufE = (float*)alloc((size_t)total * 4);
    (void)ws_size;

    hipMemsetAsync(d_ws, 0, zero_bytes, stream);

    k_detect<<<98, 256, 0, stream>>>((const unsigned int*)maskp, n / 4, flags);
    k_deg<<<(E + 255) / 256, 256, 0, stream>>>(dst, deg, E);
    k_dinv<<<(n + 255) / 256, 256, 0, stream>>>(deg, dinv, n);

    int nb1 = (n + 1 + 255) / 256;
    k_scan1<<<nb1, 256, 0, stream>>>(deg, rowptr, bsum, n);
    k_scan2<<<1, 512, 0, stream>>>(bsum, nb1);
    k_scan3<<<nb1, 256, 0, stream>>>(rowptr, bsum, n);
    k_csr<<<(E + 255) / 256, 256, 0, stream>>>(src, dst, dinv, rowptr, fill, pk, E);

    k_error<<<2048, 256, 0, stream>>>((const float4*)y_soft, y_true, maskp, flags,
                                      (float4*)bufE, psig, pcnt, total / 4);
    k_reduce<<<1, 256, 0, stream>>>(psig, pcnt, s_sig, s_cnt, 2048);

    const int pb = (n + 3) / 4;  // 4 waves per 256-thread block, 1 node per wave
    const float A1 = 0.979f, B1 = (float)(1.0 - 0.979);
    const float A2 = 0.756f, B2 = (float)(1.0 - 0.756);
    float* bufs[2] = { bufA, (float*)d_out };
    const unsigned long long* pk8 = (const unsigned long long*)pk;

    // correct phase: 10 layers, post = clip
    const float* x = bufE;
    for (int it = 0; it < 10; ++it) {
        k_prop<0><<<pb, 256, 0, stream>>>(rowptr, pk8, x, bufE, bufs[it & 1], A1, B1, n);
        x = bufs[it & 1];
    }
    // x == d_out holds smoothed_error; build y0 into bufE
    k_scale<<<pb, 256, 0, stream>>>(x, y_soft, y_true, maskp, flags, s_sig, s_cnt, bufE, n);

    // smooth phase: 10 layers, post = softmax; final layer lands in d_out
    x = bufE;
    for (int it = 0; it < 10; ++it) {
        k_prop<1><<<pb, 256, 0, stream>>>(rowptr, pk8, x, bufE, bufs[it & 1], A2, B2, n);
        x = bufs[it & 1];
    }
}

// Round 4
// 2782.196 us; speedup vs baseline: 1.0780x; 1.0780x over previous
//
#include <hip/hip_runtime.h>
#include <hip/hip_fp16.h>
#include <math.h>

#define C 40

// ---------------- mask dtype detection ----------------
__global__ void k_detect(const unsigned int* __restrict__ w, int nwords,
                         unsigned int* __restrict__ flags) {
    int i = blockIdx.x * blockDim.x + threadIdx.x;
    unsigned int viol = 0;
    for (; i < nwords; i += gridDim.x * blockDim.x) {
        unsigned int v = w[i];
        if (!(v == 0u || v == 1u)) viol |= 1u;
        if (!(v == 0u || v == 0x3F800000u)) viol |= 2u;
    }
    if (viol) atomicOr(flags, viol);
}

__device__ __forceinline__ bool read_mask(const void* mp, unsigned int fl, int n) {
    if ((fl & 1u) == 0u) return ((const int*)mp)[n] != 0;        // int32 {0,1}
    if ((fl & 2u) == 0u) return ((const float*)mp)[n] != 0.0f;   // float {0,1}
    return ((const unsigned char*)mp)[n] != 0;                   // bool bytes
}

// ---------------- degree / norm ----------------
__global__ void k_deg(const int* __restrict__ dst, int* __restrict__ deg, int E) {
    int i = blockIdx.x * blockDim.x + threadIdx.x;
    if (i < E) atomicAdd(&deg[dst[i]], 1);
}

__global__ void k_dinv(const int* __restrict__ deg, float* __restrict__ dinv, int n) {
    int i = blockIdx.x * blockDim.x + threadIdx.x;
    if (i < n) {
        int d = deg[i];
        dinv[i] = (d > 0) ? rsqrtf((float)d) : 0.0f;
    }
}

// ---------------- exclusive scan (3-phase) over deg -> rowptr ----------------
__global__ void k_scan1(const int* __restrict__ deg, int* __restrict__ rowptr,
                        int* __restrict__ bsum, int n) {
    __shared__ int sm[256];
    int tid = threadIdx.x;
    int i = blockIdx.x * 256 + tid;
    int v = (i < n) ? deg[i] : 0;
    sm[tid] = v;
    __syncthreads();
#pragma unroll
    for (int o = 1; o < 256; o <<= 1) {
        int t = (tid >= o) ? sm[tid - o] : 0;
        __syncthreads();
        sm[tid] += t;
        __syncthreads();
    }
    if (i <= n) rowptr[i] = sm[tid] - v;  // exclusive
    if (tid == 255) bsum[blockIdx.x] = sm[255];
}

__global__ void k_scan2(int* __restrict__ bsum, int nb) {
    __shared__ int sm[512];
    int tid = threadIdx.x;
    int v = (tid < nb) ? bsum[tid] : 0;
    sm[tid] = v;
    __syncthreads();
    for (int o = 1; o < 512; o <<= 1) {
        int t = (tid >= o) ? sm[tid - o] : 0;
        __syncthreads();
        sm[tid] += t;
        __syncthreads();
    }
    if (tid < nb) bsum[tid] = sm[tid] - v;  // exclusive over block sums
}

__global__ void k_scan3(int* __restrict__ rowptr, const int* __restrict__ bsum, int n) {
    int i = blockIdx.x * 256 + threadIdx.x;
    if (i <= n) rowptr[i] += bsum[blockIdx.x];
}

// ---------------- CSR scatter: pk[pos] = {src, norm} ----------------
__global__ void k_csr(const int* __restrict__ src, const int* __restrict__ dst,
                      const float* __restrict__ dinv, const int* __restrict__ rowptr,
                      int* __restrict__ fill, int2* __restrict__ pk, int E) {
    int e = blockIdx.x * blockDim.x + threadIdx.x;
    if (e < E) {
        int s = src[e], d = dst[e];
        int pos = rowptr[d] + atomicAdd(&fill[d], 1);
        int2 v = make_int2(s, __float_as_int(dinv[s] * dinv[d]));
        __builtin_nontemporal_store(*(long long*)&v, (long long*)&pk[pos]);
    }
}

// ---------------- error (half out) + block partials (no global atomics) ----------------
__global__ __launch_bounds__(256) void k_error(
    const float4* __restrict__ ys4, const int* __restrict__ y_true,
    const void* __restrict__ maskp, const unsigned int* __restrict__ flags,
    __half2* __restrict__ errh2, float* __restrict__ psig, float* __restrict__ pcnt,
    int nquads) {
    unsigned int fl = *flags;
    float a = 0.f, cnt = 0.f;
    for (int i = blockIdx.x * blockDim.x + threadIdx.x; i < nquads;
         i += gridDim.x * blockDim.x) {
        int node = i / 10;
        int q = i - node * 10;
        float4 e = make_float4(0.f, 0.f, 0.f, 0.f);
        if (read_mask(maskp, fl, node)) {
            int yt = y_true[node];
            float4 ys = ys4[i];
            int c0 = q * 4;
            e.x = ((c0 + 0) == yt ? 1.f : 0.f) - ys.x;
            e.y = ((c0 + 1) == yt ? 1.f : 0.f) - ys.y;
            e.z = ((c0 + 2) == yt ? 1.f : 0.f) - ys.z;
            e.w = ((c0 + 3) == yt ? 1.f : 0.f) - ys.w;
            a += fabsf(e.x) + fabsf(e.y) + fabsf(e.z) + fabsf(e.w);
            if (q == 0) cnt += 1.f;
        }
        errh2[i * 2] = __floats2half2_rn(e.x, e.y);
        errh2[i * 2 + 1] = __floats2half2_rn(e.z, e.w);
    }
    __shared__ float sA[256];
    __shared__ float sB[256];
    int tid = threadIdx.x;
    sA[tid] = a; sB[tid] = cnt;
    __syncthreads();
    for (int o = 128; o; o >>= 1) {
        if (tid < o) { sA[tid] += sA[tid + o]; sB[tid] += sB[tid + o]; }
        __syncthreads();
    }
    if (tid == 0) { psig[blockIdx.x] = sA[0]; pcnt[blockIdx.x] = sB[0]; }
}

__global__ __launch_bounds__(256) void k_reduce(
    const float* __restrict__ psig, const float* __restrict__ pcnt,
    float* __restrict__ s_sig, float* __restrict__ s_cnt, int nb) {
    float a = 0.f, c = 0.f;
    for (int i = threadIdx.x; i < nb; i += 256) { a += psig[i]; c += pcnt[i]; }
    __shared__ float sA[256];
    __shared__ float sB[256];
    int tid = threadIdx.x;
    sA[tid] = a; sB[tid] = c;
    __syncthreads();
    for (int o = 128; o; o >>= 1) {
        if (tid < o) { sA[tid] += sA[tid + o]; sB[tid] += sB[tid + o]; }
        __syncthreads();
    }
    if (tid == 0) { *s_sig = sA[0]; *s_cnt = sB[0]; }
}

// ---------------- propagation layer: one wave per dst node, fp16 features ----
// POST=0: clip(-1,1);  POST=1: softmax.  F32OUT=1: final layer writes fp32.
// pk loads are nontemporal (pure stream); x/y0/out are normal (L2-cached).
template <int POST, int F32OUT>
__global__ __launch_bounds__(256) void k_prop(
    const int* __restrict__ rowptr, const unsigned long long* __restrict__ pk8,
    const __half* __restrict__ x, const __half* __restrict__ y0,
    void* __restrict__ outv, float alpha, float beta, int n) {
    int wid = (blockIdx.x * blockDim.x + threadIdx.x) >> 6;
    int lane = threadIdx.x & 63;
    if (wid >= n) return;
    int beg = rowptr[wid], end = rowptr[wid + 1];
    float v = 0.f;
    if (lane < C) {
        float y0v = __half2float(y0[wid * C + lane]);
        float acc0 = 0.f, acc1 = 0.f, acc2 = 0.f, acc3 = 0.f;
        int e = beg;
        for (; e + 8 <= end; e += 8) {
            unsigned long long u0 = __builtin_nontemporal_load(pk8 + e);
            unsigned long long u1 = __builtin_nontemporal_load(pk8 + e + 1);
            unsigned long long u2 = __builtin_nontemporal_load(pk8 + e + 2);
            unsigned long long u3 = __builtin_nontemporal_load(pk8 + e + 3);
            unsigned long long u4 = __builtin_nontemporal_load(pk8 + e + 4);
            unsigned long long u5 = __builtin_nontemporal_load(pk8 + e + 5);
            unsigned long long u6 = __builtin_nontemporal_load(pk8 + e + 6);
            unsigned long long u7 = __builtin_nontemporal_load(pk8 + e + 7);
            float x0 = __half2float(x[(int)(u0 & 0xffffffffu) * C + lane]);
            float x1 = __half2float(x[(int)(u1 & 0xffffffffu) * C + lane]);
            float x2 = __half2float(x[(int)(u2 & 0xffffffffu) * C + lane]);
            float x3 = __half2float(x[(int)(u3 & 0xffffffffu) * C + lane]);
            float x4 = __half2float(x[(int)(u4 & 0xffffffffu) * C + lane]);
            float x5 = __half2float(x[(int)(u5 & 0xffffffffu) * C + lane]);
            float x6 = __half2float(x[(int)(u6 & 0xffffffffu) * C + lane]);
            float x7 = __half2float(x[(int)(u7 & 0xffffffffu) * C + lane]);
            acc0 = fmaf(__int_as_float((int)(u0 >> 32)), x0, acc0);
            acc1 = fmaf(__int_as_float((int)(u1 >> 32)), x1, acc1);
            acc2 = fmaf(__int_as_float((int)(u2 >> 32)), x2, acc2);
            acc3 = fmaf(__int_as_float((int)(u3 >> 32)), x3, acc3);
            acc0 = fmaf(__int_as_float((int)(u4 >> 32)), x4, acc0);
            acc1 = fmaf(__int_as_float((int)(u5 >> 32)), x5, acc1);
            acc2 = fmaf(__int_as_float((int)(u6 >> 32)), x6, acc2);
            acc3 = fmaf(__int_as_float((int)(u7 >> 32)), x7, acc3);
        }
        for (; e < end; ++e) {
            unsigned long long u = __builtin_nontemporal_load(pk8 + e);
            float xv = __half2float(x[(int)(u & 0xffffffffu) * C + lane]);
            acc0 = fmaf(__int_as_float((int)(u >> 32)), xv, acc0);
        }
        float a = (acc0 + acc1) + (acc2 + acc3);
        v = fmaf(alpha, a, beta * y0v);
    }
    float res;
    if (POST == 0) {
        res = fminf(1.0f, fmaxf(-1.0f, v));
    } else {
        float mx = (lane < C) ? v : -3.0e38f;
#pragma unroll
        for (int o = 32; o; o >>= 1) mx = fmaxf(mx, __shfl_xor(mx, o));
        float ex = (lane < C) ? __expf(v - mx) : 0.0f;
        float s = ex;
#pragma unroll
        for (int o = 32; o; o >>= 1) s += __shfl_xor(s, o);
        res = ex / s;
    }
    if (lane < C) {
        if (F32OUT) ((float*)outv)[wid * C + lane] = res;
        else        ((__half*)outv)[wid * C + lane] = __float2half(res);
    }
}

// ---------------- scale + y0 build (half in/out): one wave per node ----------------
__global__ __launch_bounds__(256) void k_scale(
    const __half* __restrict__ sm_err, const float* __restrict__ y_soft,
    const int* __restrict__ y_true, const void* __restrict__ maskp,
    const unsigned int* __restrict__ flags, const float* __restrict__ s_sig,
    const float* __restrict__ s_cnt, __half* __restrict__ y0, int n) {
    int wid = (blockIdx.x * blockDim.x + threadIdx.x) >> 6;
    int lane = threadIdx.x & 63;
    if (wid >= n) return;
    float v = 0.f, a = 0.f;
    if (lane < C) {
        v = __half2float(sm_err[wid * C + lane]);
        a = fabsf(v);
    }
#pragma unroll
    for (int o = 32; o; o >>= 1) a += __shfl_xor(a, o);
    float sigma = (*s_sig) / (*s_cnt);
    float scale = sigma / a;
    if (isinf(scale) || scale > 1000.0f) scale = 1.0f;
    if (lane < C) {
        bool m = read_mask(maskp, *flags, wid);
        float yc = fmaf(scale, v, y_soft[wid * C + lane]);
        y0[wid * C + lane] = __float2half(m ? ((lane == y_true[wid]) ? 1.0f : 0.0f) : yc);
    }
}

extern "C" void kernel_launch(void* const* d_in, const int* in_sizes, int n_in,
                              void* d_out, int out_size, void* d_ws, size_t ws_size,
                              hipStream_t stream) {
    const int* y_true = (const int*)d_in[0];
    const float* y_soft = (const float*)d_in[1];
    const void* maskp = d_in[2];
    const int* ei = (const int*)d_in[3];
    const int n = in_sizes[0];
    const int total = in_sizes[1];          // n * C
    const int E = in_sizes[3] / 2;
    const int* src = ei;
    const int* dst = ei + E;

    char* ws = (char*)d_ws;
    size_t off = 0;
    auto alloc = [&](size_t bytes) -> char* {
        char* p = ws + off;
        off += (bytes + 63) & ~(size_t)63;
        return p;
    };
    int* deg = (int*)alloc((size_t)n * 4);
    int* fill = (int*)alloc((size_t)n * 4);
    unsigned int* flags = (unsigned int*)alloc(4);
    size_t zero_bytes = off;                 // zero everything above each call
    float* s_sig = (float*)alloc(4);
    float* s_cnt = (float*)alloc(4);
    float* psig = (float*)alloc(2048 * 4);
    float* pcnt = (float*)alloc(2048 * 4);
    float* dinv = (float*)alloc((size_t)n * 4);
    int* rowptr = (int*)alloc((size_t)(n + 1) * 4);
    int* bsum = (int*)alloc(4096);
    int2* pk = (int2*)alloc((size_t)E * 8);
    __half* hE = (__half*)alloc((size_t)total * 2);   // error / correct-phase y0
    __half* hY = (__half*)alloc((size_t)total * 2);   // smooth-phase y0
    __half* hA = (__half*)alloc((size_t)total * 2);   // ping
    __half* hB = (__half*)alloc((size_t)total * 2);   // pong
    (void)ws_size;

    hipMemsetAsync(d_ws, 0, zero_bytes, stream);

    k_detect<<<98, 256, 0, stream>>>((const unsigned int*)maskp, n / 4, flags);
    k_deg<<<(E + 255) / 256, 256, 0, stream>>>(dst, deg, E);
    k_dinv<<<(n + 255) / 256, 256, 0, stream>>>(deg, dinv, n);

    int nb1 = (n + 1 + 255) / 256;
    k_scan1<<<nb1, 256, 0, stream>>>(deg, rowptr, bsum, n);
    k_scan2<<<1, 512, 0, stream>>>(bsum, nb1);
    k_scan3<<<nb1, 256, 0, stream>>>(rowptr, bsum, n);
    k_csr<<<(E + 255) / 256, 256, 0, stream>>>(src, dst, dinv, rowptr, fill, pk, E);

    k_error<<<2048, 256, 0, stream>>>((const float4*)y_soft, y_true, maskp, flags,
                                      (__half2*)hE, psig, pcnt, total / 4);
    k_reduce<<<1, 256, 0, stream>>>(psig, pcnt, s_sig, s_cnt, 2048);

    const int pb = (n + 3) / 4;  // 4 waves per 256-thread block, 1 node per wave
    const float A1 = 0.979f, B1 = (float)(1.0 - 0.979);
    const float A2 = 0.756f, B2 = (float)(1.0 - 0.756);
    __half* bufs[2] = { hA, hB };
    const unsigned long long* pk8 = (const unsigned long long*)pk;

    // correct phase: 10 layers, post = clip, all fp16
    const __half* x = hE;
    for (int it = 0; it < 10; ++it) {
        k_prop<0, 0><<<pb, 256, 0, stream>>>(rowptr, pk8, x, hE, bufs[it & 1], A1, B1, n);
        x = bufs[it & 1];
    }
    // x holds smoothed_error (fp16); build y0 into hY
    k_scale<<<pb, 256, 0, stream>>>(x, y_soft, y_true, maskp, flags, s_sig, s_cnt, hY, n);

    // smooth phase: 10 layers, post = softmax; final layer writes fp32 d_out
    x = hY;
    for (int it = 0; it < 9; ++it) {
        k_prop<1, 0><<<pb, 256, 0, stream>>>(rowptr, pk8, x, hY, bufs[it & 1], A2, B2, n);
        x = bufs[it & 1];
    }
    k_prop<1, 1><<<pb, 256, 0, stream>>>(rowptr, pk8, x, hY, d_out, A2, B2, n);
}

// Round 5
// 1590.159 us; speedup vs baseline: 1.8861x; 1.7496x over previous
//
#include <hip/hip_runtime.h>
#include <hip/hip_fp16.h>
#include <math.h>

#define C 40

// ---------------- mask dtype detection ----------------
__global__ void k_detect(const unsigned int* __restrict__ w, int nwords,
                         unsigned int* __restrict__ flags) {
    int i = blockIdx.x * blockDim.x + threadIdx.x;
    unsigned int viol = 0;
    for (; i < nwords; i += gridDim.x * blockDim.x) {
        unsigned int v = w[i];
        if (!(v == 0u || v == 1u)) viol |= 1u;
        if (!(v == 0u || v == 0x3F800000u)) viol |= 2u;
    }
    if (viol) atomicOr(flags, viol);
}

__device__ __forceinline__ bool read_mask(const void* mp, unsigned int fl, int n) {
    if ((fl & 1u) == 0u) return ((const int*)mp)[n] != 0;        // int32 {0,1}
    if ((fl & 2u) == 0u) return ((const float*)mp)[n] != 0.0f;   // float {0,1}
    return ((const unsigned char*)mp)[n] != 0;                   // bool bytes
}

// ---------------- degree / norm ----------------
__global__ void k_deg(const int* __restrict__ dst, int* __restrict__ deg, int E) {
    int i = blockIdx.x * blockDim.x + threadIdx.x;
    if (i < E) atomicAdd(&deg[dst[i]], 1);
}

__global__ void k_dinv(const int* __restrict__ deg, float* __restrict__ dinv, int n) {
    int i = blockIdx.x * blockDim.x + threadIdx.x;
    if (i < n) {
        int d = deg[i];
        dinv[i] = (d > 0) ? rsqrtf((float)d) : 0.0f;
    }
}

// ---------------- exclusive scan (3-phase) over deg -> rowptr ----------------
__global__ void k_scan1(const int* __restrict__ deg, int* __restrict__ rowptr,
                        int* __restrict__ bsum, int n) {
    __shared__ int sm[256];
    int tid = threadIdx.x;
    int i = blockIdx.x * 256 + tid;
    int v = (i < n) ? deg[i] : 0;
    sm[tid] = v;
    __syncthreads();
#pragma unroll
    for (int o = 1; o < 256; o <<= 1) {
        int t = (tid >= o) ? sm[tid - o] : 0;
        __syncthreads();
        sm[tid] += t;
        __syncthreads();
    }
    if (i <= n) rowptr[i] = sm[tid] - v;  // exclusive
    if (tid == 255) bsum[blockIdx.x] = sm[255];
}

__global__ void k_scan2(int* __restrict__ bsum, int nb) {
    __shared__ int sm[512];
    int tid = threadIdx.x;
    int v = (tid < nb) ? bsum[tid] : 0;
    sm[tid] = v;
    __syncthreads();
    for (int o = 1; o < 512; o <<= 1) {
        int t = (tid >= o) ? sm[tid - o] : 0;
        __syncthreads();
        sm[tid] += t;
        __syncthreads();
    }
    if (tid < nb) bsum[tid] = sm[tid] - v;  // exclusive over block sums
}

__global__ void k_scan3(int* __restrict__ rowptr, const int* __restrict__ bsum, int n) {
    int i = blockIdx.x * 256 + threadIdx.x;
    if (i <= n) rowptr[i] += bsum[blockIdx.x];
}

// ---------------- CSR scatter: pk[pos] = {src, norm} ----------------
__global__ void k_csr(const int* __restrict__ src, const int* __restrict__ dst,
                      const float* __restrict__ dinv, const int* __restrict__ rowptr,
                      int* __restrict__ fill, int2* __restrict__ pk, int E) {
    int e = blockIdx.x * blockDim.x + threadIdx.x;
    if (e < E) {
        int s = src[e], d = dst[e];
        int pos = rowptr[d] + atomicAdd(&fill[d], 1);
        int2 v = make_int2(s, __float_as_int(dinv[s] * dinv[d]));
        __builtin_nontemporal_store(*(long long*)&v, (long long*)&pk[pos]);
    }
}

// ---------------- error (half out) + block partials (no global atomics) ----------------
__global__ __launch_bounds__(256) void k_error(
    const float4* __restrict__ ys4, const int* __restrict__ y_true,
    const void* __restrict__ maskp, const unsigned int* __restrict__ flags,
    __half2* __restrict__ errh2, float* __restrict__ psig, float* __restrict__ pcnt,
    int nquads) {
    unsigned int fl = *flags;
    float a = 0.f, cnt = 0.f;
    for (int i = blockIdx.x * blockDim.x + threadIdx.x; i < nquads;
         i += gridDim.x * blockDim.x) {
        int node = i / 10;
        int q = i - node * 10;
        float4 e = make_float4(0.f, 0.f, 0.f, 0.f);
        if (read_mask(maskp, fl, node)) {
            int yt = y_true[node];
            float4 ys = ys4[i];
            int c0 = q * 4;
            e.x = ((c0 + 0) == yt ? 1.f : 0.f) - ys.x;
            e.y = ((c0 + 1) == yt ? 1.f : 0.f) - ys.y;
            e.z = ((c0 + 2) == yt ? 1.f : 0.f) - ys.z;
            e.w = ((c0 + 3) == yt ? 1.f : 0.f) - ys.w;
            a += fabsf(e.x) + fabsf(e.y) + fabsf(e.z) + fabsf(e.w);
            if (q == 0) cnt += 1.f;
        }
        errh2[i * 2] = __floats2half2_rn(e.x, e.y);
        errh2[i * 2 + 1] = __floats2half2_rn(e.z, e.w);
    }
    __shared__ float sA[256];
    __shared__ float sB[256];
    int tid = threadIdx.x;
    sA[tid] = a; sB[tid] = cnt;
    __syncthreads();
    for (int o = 128; o; o >>= 1) {
        if (tid < o) { sA[tid] += sA[tid + o]; sB[tid] += sB[tid + o]; }
        __syncthreads();
    }
    if (tid == 0) { psig[blockIdx.x] = sA[0]; pcnt[blockIdx.x] = sB[0]; }
}

__global__ __launch_bounds__(256) void k_reduce(
    const float* __restrict__ psig, const float* __restrict__ pcnt,
    float* __restrict__ s_sig, float* __restrict__ s_cnt, int nb) {
    float a = 0.f, c = 0.f;
    for (int i = threadIdx.x; i < nb; i += 256) { a += psig[i]; c += pcnt[i]; }
    __shared__ float sA[256];
    __shared__ float sB[256];
    int tid = threadIdx.x;
    sA[tid] = a; sB[tid] = c;
    __syncthreads();
    for (int o = 128; o; o >>= 1) {
        if (tid < o) { sA[tid] += sA[tid + o]; sB[tid] += sB[tid + o]; }
        __syncthreads();
    }
    if (tid == 0) { *s_sig = sA[0]; *s_cnt = sB[0]; }
}

// ---------------- propagation layer: one wave per dst node, fp16 features ----
// pk offsets forced wave-uniform via readfirstlane -> compiler emits scalar
// (s_load) broadcasts on the LGKM pipe; VMEM pipe is gathers only.
// Inner loop branch-free: lanes >= C broadcast-read byte 0..1 of the row
// (same cache line as lane 0 -> no extra traffic); masking in epilogue only.
#define PKLOAD(U, EE)                                                        \
    _Pragma("unroll") for (int j = 0; j < GRP; ++j) { U[j] = pk8[(EE) + j]; }

#define GATH(XV, U)                                                          \
    _Pragma("unroll") for (int j = 0; j < GRP; ++j) {                        \
        XV[j] = x[(int)(U[j] & 0xffffffffu) * C + gl];                       \
    }

#define FMAG(U, XV)                                                          \
    _Pragma("unroll") for (int j = 0; j < GRP; ++j) {                        \
        acc[j & 3] = fmaf(__int_as_float((int)(U[j] >> 32)),                 \
                          __half2float(XV[j]), acc[j & 3]);                  \
    }

template <int POST, int F32OUT>
__global__ __launch_bounds__(256) void k_prop(
    const int* __restrict__ rowptr, const unsigned long long* __restrict__ pk8,
    const __half* __restrict__ x, const __half* __restrict__ y0,
    void* __restrict__ outv, float alpha, float beta, int n) {
    int wid = (blockIdx.x * blockDim.x + threadIdx.x) >> 6;
    int lane = threadIdx.x & 63;
    if (wid >= n) return;
    int beg = __builtin_amdgcn_readfirstlane(rowptr[wid]);
    int end = __builtin_amdgcn_readfirstlane(rowptr[wid + 1]);
    int gl = (lane < C) ? lane : 0;  // clamped gather lane (no OOB, no branch)
    float y0v = __half2float(y0[wid * C + gl]);
    float acc[4] = {0.f, 0.f, 0.f, 0.f};
    int e = beg;
    {
        enum { GRP = 16 };
        for (; e + GRP <= end; e += GRP) {
            unsigned long long u[GRP];
            __half xv[GRP];
            PKLOAD(u, e)
            GATH(xv, u)
            FMAG(u, xv)
        }
    }
    {
        enum { GRP = 8 };
        if (e + GRP <= end) {
            unsigned long long u[GRP];
            __half xv[GRP];
            PKLOAD(u, e)
            GATH(xv, u)
            FMAG(u, xv)
            e += GRP;
        }
    }
    for (; e < end; ++e) {
        unsigned long long u = pk8[e];
        float xv = __half2float(x[(int)(u & 0xffffffffu) * C + gl]);
        acc[0] = fmaf(__int_as_float((int)(u >> 32)), xv, acc[0]);
    }
    float a = (acc[0] + acc[1]) + (acc[2] + acc[3]);
    float v = fmaf(alpha, a, beta * y0v);

    if (POST == 0) {
        if (lane < C) {
            float res = fminf(1.0f, fmaxf(-1.0f, v));
            if (F32OUT) ((float*)outv)[wid * C + lane] = res;
            else        ((__half*)outv)[wid * C + lane] = __float2half(res);
        }
    } else {
        float mx = (lane < C) ? v : -3.0e38f;
#pragma unroll
        for (int o = 32; o; o >>= 1) mx = fmaxf(mx, __shfl_xor(mx, o));
        float ex = (lane < C) ? __expf(v - mx) : 0.0f;
        float s = ex;
#pragma unroll
        for (int o = 32; o; o >>= 1) s += __shfl_xor(s, o);
        if (lane < C) {
            float res = ex / s;
            if (F32OUT) ((float*)outv)[wid * C + lane] = res;
            else        ((__half*)outv)[wid * C + lane] = __float2half(res);
        }
    }
}

// ---------------- scale + y0 build (half in/out): one wave per node ----------------
__global__ __launch_bounds__(256) void k_scale(
    const __half* __restrict__ sm_err, const float* __restrict__ y_soft,
    const int* __restrict__ y_true, const void* __restrict__ maskp,
    const unsigned int* __restrict__ flags, const float* __restrict__ s_sig,
    const float* __restrict__ s_cnt, __half* __restrict__ y0, int n) {
    int wid = (blockIdx.x * blockDim.x + threadIdx.x) >> 6;
    int lane = threadIdx.x & 63;
    if (wid >= n) return;
    float v = 0.f, a = 0.f;
    if (lane < C) {
        v = __half2float(sm_err[wid * C + lane]);
        a = fabsf(v);
    }
#pragma unroll
    for (int o = 32; o; o >>= 1) a += __shfl_xor(a, o);
    float sigma = (*s_sig) / (*s_cnt);
    float scale = sigma / a;
    if (isinf(scale) || scale > 1000.0f) scale = 1.0f;
    if (lane < C) {
        bool m = read_mask(maskp, *flags, wid);
        float yc = fmaf(scale, v, y_soft[wid * C + lane]);
        y0[wid * C + lane] = __float2half(m ? ((lane == y_true[wid]) ? 1.0f : 0.0f) : yc);
    }
}

extern "C" void kernel_launch(void* const* d_in, const int* in_sizes, int n_in,
                              void* d_out, int out_size, void* d_ws, size_t ws_size,
                              hipStream_t stream) {
    const int* y_true = (const int*)d_in[0];
    const float* y_soft = (const float*)d_in[1];
    const void* maskp = d_in[2];
    const int* ei = (const int*)d_in[3];
    const int n = in_sizes[0];
    const int total = in_sizes[1];          // n * C
    const int E = in_sizes[3] / 2;
    const int* src = ei;
    const int* dst = ei + E;

    char* ws = (char*)d_ws;
    size_t off = 0;
    auto alloc = [&](size_t bytes) -> char* {
        char* p = ws + off;
        off += (bytes + 63) & ~(size_t)63;
        return p;
    };
    int* deg = (int*)alloc((size_t)n * 4);
    int* fill = (int*)alloc((size_t)n * 4);
    unsigned int* flags = (unsigned int*)alloc(4);
    size_t zero_bytes = off;                 // zero everything above each call
    float* s_sig = (float*)alloc(4);
    float* s_cnt = (float*)alloc(4);
    float* psig = (float*)alloc(2048 * 4);
    float* pcnt = (float*)alloc(2048 * 4);
    float* dinv = (float*)alloc((size_t)n * 4);
    int* rowptr = (int*)alloc((size_t)(n + 1) * 4);
    int* bsum = (int*)alloc(4096);
    int2* pk = (int2*)alloc((size_t)E * 8);
    size_t fbytes = (size_t)total * 2 + 256;  // slack for clamped-lane reads
    __half* hE = (__half*)alloc(fbytes);   // error / correct-phase y0
    __half* hY = (__half*)alloc(fbytes);   // smooth-phase y0
    __half* hA = (__half*)alloc(fbytes);   // ping
    __half* hB = (__half*)alloc(fbytes);   // pong
    (void)ws_size;

    hipMemsetAsync(d_ws, 0, zero_bytes, stream);

    k_detect<<<98, 256, 0, stream>>>((const unsigned int*)maskp, n / 4, flags);
    k_deg<<<(E + 255) / 256, 256, 0, stream>>>(dst, deg, E);
    k_dinv<<<(n + 255) / 256, 256, 0, stream>>>(deg, dinv, n);

    int nb1 = (n + 1 + 255) / 256;
    k_scan1<<<nb1, 256, 0, stream>>>(deg, rowptr, bsum, n);
    k_scan2<<<1, 512, 0, stream>>>(bsum, nb1);
    k_scan3<<<nb1, 256, 0, stream>>>(rowptr, bsum, n);
    k_csr<<<(E + 255) / 256, 256, 0, stream>>>(src, dst, dinv, rowptr, fill, pk, E);

    k_error<<<2048, 256, 0, stream>>>((const float4*)y_soft, y_true, maskp, flags,
                                      (__half2*)hE, psig, pcnt, total / 4);
    k_reduce<<<1, 256, 0, stream>>>(psig, pcnt, s_sig, s_cnt, 2048);

    const int pb = (n + 3) / 4;  // 4 waves per 256-thread block, 1 node per wave
    const float A1 = 0.979f, B1 = (float)(1.0 - 0.979);
    const float A2 = 0.756f, B2 = (float)(1.0 - 0.756);
    __half* bufs[2] = { hA, hB };
    const unsigned long long* pk8 = (const unsigned long long*)pk;

    // correct phase: 10 layers, post = clip, all fp16
    const __half* x = hE;
    for (int it = 0; it < 10; ++it) {
        k_prop<0, 0><<<pb, 256, 0, stream>>>(rowptr, pk8, x, hE, bufs[it & 1], A1, B1, n);
        x = bufs[it & 1];
    }
    // x holds smoothed_error (fp16); build y0 into hY
    k_scale<<<pb, 256, 0, stream>>>(x, y_soft, y_true, maskp, flags, s_sig, s_cnt, hY, n);

    // smooth phase: 10 layers, post = softmax; final layer writes fp32 d_out
    x = hY;
    for (int it = 0; it < 9; ++it) {
        k_prop<1, 0><<<pb, 256, 0, stream>>>(rowptr, pk8, x, hY, bufs[it & 1], A2, B2, n);
        x = bufs[it & 1];
    }
    k_prop<1, 1><<<pb, 256, 0, stream>>>(rowptr, pk8, x, hY, d_out, A2, B2, n);
}